// Round 14
// baseline (185.387 us; speedup 1.0000x reference)
//
#include <hip/hip_runtime.h>

// Branch MLP: B=16384 rows, E=4 experts, 512->1024->1024->512, relu/relu/tanh.
// Bucket rows by expert, pad to 128-row granularity with duplicate rows.
// gemm1/gemm2: faithful m201-style 8-phase 256x256 BK=64 dbuf schedule:
//   per K-tile 4 phases {ds_read changed operand half (8 or 4 b128) ->
//   stage 1 half-tile of t+1 (A0,B0,B1,A1 order) -> counted vmcnt(4) ->
//   barrier -> setprio MFMA x16 -> barrier}. Two barriers/phase close the
//   cross-tile WAR window (stage vs slow-wave reads) via lgkm-before-MFMA.
//   T1 bijective XCD swizzle on the 272-block grid. Chunk-XOR LDS swizzle.
// gemm3: R8-proven 128x128 BK=64 2-barrier kernel (tanh + f32 scatter out).
//
// Workspace (86.1 MB): ctrl[64] | t256E[96] | t256B[96] | t128E[192] |
//   t128B[320] | perm@ctrl+768 | Wt1@131072 | Wt2 | Wt3 | h1 | h2 | xp=h2.

#define B_N   16384
#define DIN   512
#define HID   1024
#define DOUT  512
#define MAXT256 68
#define MAXT128 136

typedef __attribute__((ext_vector_type(8))) short bf16x8;
typedef __attribute__((ext_vector_type(4))) float f32x4;
typedef __attribute__((address_space(3))) unsigned int lds_u32;
typedef const __attribute__((address_space(1))) unsigned int glb_u32;

__device__ __forceinline__ void gll16(const void* g, void* l) {
    __builtin_amdgcn_global_load_lds((glb_u32*)g, (lds_u32*)l, 16, 0, 0);
}

__device__ __forceinline__ unsigned short f2bf(float f) {
    unsigned int u = __float_as_uint(f);
    u += 0x7FFFu + ((u >> 16) & 1u);   // RNE
    return (unsigned short)(u >> 16);
}

__device__ __forceinline__ float fast_tanh(float x) {
    x = fminf(fmaxf(x, -9.0f), 9.0f);
    float t = __builtin_amdgcn_exp2f(x * 2.8853900817779268f);
    return (t - 1.0f) * __builtin_amdgcn_rcpf(t + 1.0f);
}

// One block: histogram cmd, cursors, and BOTH tile plans.
__global__ void plan_all_k(const int* __restrict__ cmd, int* __restrict__ ctrl,
                           int* __restrict__ t256E, int* __restrict__ t256B,
                           int* __restrict__ t128E, int* __restrict__ t128B) {
    __shared__ int h[4];
    int tid = threadIdx.x;
    if (tid < 4) h[tid] = 0;
    __syncthreads();
    int c0 = 0, c1 = 0, c2 = 0, c3 = 0;
    for (int i = tid; i < B_N; i += 256) {
        int e = cmd[i] & 3;
        c0 += (e == 0); c1 += (e == 1); c2 += (e == 2); c3 += (e == 3);
    }
    atomicAdd(&h[0], c0); atomicAdd(&h[1], c1);
    atomicAdd(&h[2], c2); atomicAdd(&h[3], c3);
    __syncthreads();
    if (tid == 0) {
        int P = 0, n256 = 0, n128 = 0;
        for (int e = 0; e < 4; ++e) {
            ctrl[e] = h[e];
            ctrl[4 + e] = 0;
            ctrl[8 + e] = P;
            int cp = ((h[e] + 127) >> 7) << 7;       // 128-padded count
            int nfull = cp >> 8;
            for (int t = 0; t < nfull; ++t) {
                t256E[n256] = e; t256B[n256] = P + t * 256; ++n256;
            }
            if (cp & 128) {                           // 128-row tail tile
                t256E[n256] = e | 4; t256B[n256] = P + nfull * 256; ++n256;
            }
            int nt = cp >> 7;
            for (int t = 0; t < nt; ++t) {
                t128E[n128] = e; t128B[n128] = P + t * 128; ++n128;
            }
            P += cp;
        }
        ctrl[12] = P;      // total padded rows
        ctrl[13] = n256;   // 256-tiles (<= 67)
        ctrl[14] = n128;   // 128-tiles (<= 131)
    }
}

// Wave-aggregated scatter: one atomicAdd(popcount) per wave per expert.
__global__ void scatter_k(const int* __restrict__ cmd, int* __restrict__ ctrl,
                          int* __restrict__ perm) {
    int i = blockIdx.x * 256 + threadIdx.x;
    int e = cmd[i] & 3;
    int lane = threadIdx.x & 63;
#pragma unroll
    for (int ee = 0; ee < 4; ++ee) {
        unsigned long long mask = __ballot(e == ee);
        if (e == ee) {
            int leader = __ffsll((unsigned long long)mask) - 1;
            int rank = __popcll(mask & ((1ull << lane) - 1ull));
            int wbase = 0;
            if (lane == leader)
                wbase = atomicAdd(&ctrl[4 + ee], __popcll(mask));
            wbase = __builtin_amdgcn_readfirstlane(wbase);
            perm[ctrl[8 + ee] + wbase + rank] = i;
        }
    }
}

// Fused prep: blocks [0,8192) transpose+convert weights; blocks [8192,12416)
// gather x -> permuted bf16 xp (4 rows/block) and fill pad perm entries.
__global__ __launch_bounds__(256) void prep_data_k(
    const float* __restrict__ W1, const float* __restrict__ W2,
    const float* __restrict__ W3, unsigned short* __restrict__ Wt1,
    unsigned short* __restrict__ Wt2, unsigned short* __restrict__ Wt3,
    const float* __restrict__ x, unsigned short* __restrict__ xp,
    int* __restrict__ perm, const int* __restrict__ ctrl)
{
    int b = blockIdx.x;
    if (b < 8192) {
        int e = b >> 11, r = b & 2047;
        const float* W; unsigned short* Wt; int KD, ND, kt, nt;
        if (r < 512)       { W = W1; Wt = Wt1; KD = 512;  ND = 1024; kt = r & 15;           nt = r >> 4; }
        else if (r < 1536) { W = W2; Wt = Wt2; KD = 1024; ND = 1024; kt = (r - 512) & 31;   nt = (r - 512) >> 5; }
        else               { W = W3; Wt = Wt3; KD = 1024; ND = 512;  kt = (r - 1536) & 31;  nt = (r - 1536) >> 5; }
        __shared__ float t[32][33];
        size_t base = (size_t)e * KD * ND;
        int k0 = kt * 32, n0 = nt * 32;
        int tx = threadIdx.x & 31, ty = threadIdx.x >> 5;
#pragma unroll
        for (int s = 0; s < 4; ++s)
            t[ty + s * 8][tx] = W[base + (size_t)(k0 + ty + s * 8) * ND + n0 + tx];
        __syncthreads();
#pragma unroll
        for (int s = 0; s < 4; ++s)
            Wt[base + (size_t)(n0 + ty + s * 8) * KD + k0 + tx] = f2bf(t[tx][ty + s * 8]);
    } else {
        int g = b - 8192;
        int p = g * 4 + (int)(threadIdx.x >> 6);
        if (p >= ctrl[12]) return;
        int lane = threadIdx.x & 63;
        int e = (p >= ctrl[9]) + (p >= ctrl[10]) + (p >= ctrl[11]);
        int segBase = ctrl[8 + e];
        int src;
        if (p < segBase + ctrl[e]) {
            src = perm[p];
        } else {
            src = perm[segBase];              // duplicate a valid same-expert row
            if (lane == 0) perm[p] = src;     // so gemm3 scatter-epilogue is safe
        }
        const float* xr = x + (size_t)src * DIN + lane * 8;
        float4 a = *(const float4*)xr;
        float4 c = *(const float4*)(xr + 4);
        uint4 o;
        o.x = (unsigned)f2bf(a.x) | ((unsigned)f2bf(a.y) << 16);
        o.y = (unsigned)f2bf(a.z) | ((unsigned)f2bf(a.w) << 16);
        o.z = (unsigned)f2bf(c.x) | ((unsigned)f2bf(c.y) << 16);
        o.w = (unsigned)f2bf(c.z) | ((unsigned)f2bf(c.w) << 16);
        *(uint4*)(xp + (size_t)p * DIN + lane * 8) = o;
    }
}

#define VMW(n) asm volatile("s_waitcnt vmcnt(" #n ")" ::: "memory")
#define BAR  do { asm volatile("" ::: "memory"); __builtin_amdgcn_s_barrier(); \
                  asm volatile("" ::: "memory"); } while (0)

// 8-phase 256x256 grouped GEMM (relu, bf16 out), N = HID.
template<int K>
__global__ __launch_bounds__(512) void gemm8_k(
    const unsigned short* __restrict__ A, const unsigned short* __restrict__ Bt,
    const float* __restrict__ bias, unsigned short* __restrict__ Outp,
    const int* __restrict__ ctrl, const int* __restrict__ t256E,
    const int* __restrict__ t256B)
{
    constexpr int N = HID;
    __shared__ unsigned short LDS[65536];   // 128KB: buf*32768 + {A:0 | B:16384}

    // T1 bijective XCD swizzle (272 = 8*34 blocks)
    const int l = (int)blockIdx.x + MAXT256 * (int)blockIdx.y;
    const int swz = (l & 7) * 34 + (l >> 3);
    const int tile = swz >> 2, panel = swz & 3;
    if (tile >= ctrl[13]) return;
    const int te = t256E[tile];
    const int e = te & 3;
    const int TM = (te & 4) ? 128 : 256;
    const int wrapMask = TM - 1;
    const int rowBase = t256B[tile];
    const int n0 = panel * 256;

    const int tid = threadIdx.x;
    const int lane = tid & 63;
    const int w = tid >> 6;
    const int wm = w >> 2, wn = w & 3;      // 2M x 4N waves
    const int lr = lane & 15, lh = lane >> 4;

    f32x4 acc[2][2][4][2] = {};             // [MH][NH][mi][niL]
    bf16x8 afr[4][2], bfr[2][2];

    const int tr = tid >> 3, tc = tid & 7;
    const int cs = (tc ^ (tr & 7)) * 8;     // swizzled source chunk (row&7==tr&7)
    size_t aoff[2][2], boff[2][2];          // [half][call]
#pragma unroll
    for (int h = 0; h < 2; ++h)
#pragma unroll
        for (int j = 0; j < 2; ++j) {
            aoff[h][j] = (size_t)(rowBase + ((h * 128 + j * 64 + tr) & wrapMask)) * K + cs;
            boff[h][j] = ((size_t)e * N + n0 + h * 128 + j * 64 + tr) * K + cs;
        }
    const int ksl0 = (lh ^ (lr & 7)) * 8;
    const int ksl1 = ((4 + lh) ^ (lr & 7)) * 8;

#define SA(tt, h) do { const int _tb = ((tt) & 1) * 32768, _k = (tt) * 64;     \
        gll16(A + aoff[h][0] + _k, &LDS[_tb + (h) * 8192 + tid * 8]);          \
        gll16(A + aoff[h][1] + _k, &LDS[_tb + (h) * 8192 + 4096 + tid * 8]); } while (0)
#define SB(tt, h) do { const int _tb = ((tt) & 1) * 32768, _k = (tt) * 64;     \
        gll16(Bt + boff[h][0] + _k, &LDS[_tb + 16384 + (h) * 8192 + tid * 8]); \
        gll16(Bt + boff[h][1] + _k, &LDS[_tb + 16384 + (h) * 8192 + 4096 + tid * 8]); } while (0)
#define LDA(tb, MH) _Pragma("unroll") for (int mi = 0; mi < 4; ++mi) {         \
        int ar = (MH) * 128 + wm * 64 + mi * 16 + lr;                          \
        afr[mi][0] = *(const bf16x8*)&LDS[(tb) * 32768 + ar * 64 + ksl0];      \
        afr[mi][1] = *(const bf16x8*)&LDS[(tb) * 32768 + ar * 64 + ksl1]; }
#define LDB(tb, NH) _Pragma("unroll") for (int ni = 0; ni < 2; ++ni) {         \
        int br = (NH) * 128 + wn * 32 + ni * 16 + lr;                          \
        bfr[ni][0] = *(const bf16x8*)&LDS[(tb) * 32768 + 16384 + br * 64 + ksl0]; \
        bfr[ni][1] = *(const bf16x8*)&LDS[(tb) * 32768 + 16384 + br * 64 + ksl1]; }
#define MM(MH, NH) do { __builtin_amdgcn_s_setprio(1);                         \
        _Pragma("unroll") for (int mi = 0; mi < 4; ++mi)                       \
        _Pragma("unroll") for (int ni = 0; ni < 2; ++ni) {                     \
            acc[MH][NH][mi][ni] = __builtin_amdgcn_mfma_f32_16x16x32_bf16(     \
                afr[mi][0], bfr[ni][0], acc[MH][NH][mi][ni], 0, 0, 0);         \
            acc[MH][NH][mi][ni] = __builtin_amdgcn_mfma_f32_16x16x32_bf16(     \
                afr[mi][1], bfr[ni][1], acc[MH][NH][mi][ni], 0, 0, 0);         \
        }                                                                      \
        __builtin_amdgcn_s_setprio(0); } while (0)

    constexpr int NT = K / 64;
    // prologue: tile 0 staged in first-use order A0,B0,B1,A1
    SA(0, 0); SB(0, 0); SB(0, 1); SA(0, 1);
    VMW(4); BAR;                            // A0,B0 of tile 0 landed
    for (int t = 0; t < NT; ++t) {
        const int tb = t & 1;
        const bool nl = (t + 1 < NT);
        // P1 (0,0): reads A0+B0 of tile t; stages A0 of t+1
        LDA(tb, 0); LDB(tb, 0);
        if (nl) { SA(t + 1, 0); VMW(4); } else { VMW(2); }   // -> B1(t) landed
        BAR; MM(0, 0); BAR;
        // P2 (0,1): reads B1 (A0 in regs); stages B0 of t+1
        LDB(tb, 1);
        if (nl) { SB(t + 1, 0); VMW(4); } else { VMW(0); }   // -> A1(t) landed
        BAR; MM(0, 1); BAR;
        // P3 (1,1): reads A1 (B1 in regs); stages B1 of t+1
        LDA(tb, 1);
        if (nl) SB(t + 1, 1);
        BAR; MM(1, 1); BAR;
        // P4 (1,0): re-reads B0 (A1 in regs); stages A1 of t+1
        LDB(tb, 0);
        if (nl) { SA(t + 1, 1); VMW(4); }   // -> A0,B0(t+1) landed for next P1
        BAR; MM(1, 0); BAR;
    }
#undef SA
#undef SB
#undef LDA
#undef LDB
#undef MM

    // epilogue: bias + relu + bf16 store (skip MH=1 rows for 128-row tails)
#pragma unroll
    for (int mh = 0; mh < 2; ++mh) {
        if (!(TM == 128 && mh == 1)) {
#pragma unroll
            for (int nh = 0; nh < 2; ++nh)
#pragma unroll
                for (int ni = 0; ni < 2; ++ni) {
                    int col = n0 + nh * 128 + wn * 32 + ni * 16 + lr;
                    float bv = bias[e * N + col];
#pragma unroll
                    for (int mi = 0; mi < 4; ++mi)
#pragma unroll
                        for (int r = 0; r < 4; ++r) {
                            int rowL = mh * 128 + wm * 64 + mi * 16 + lh * 4 + r;
                            float v = acc[mh][nh][mi][ni][r] + bv;
                            v = fmaxf(v, 0.0f);
                            Outp[(size_t)(rowBase + rowL) * N + col] = f2bf(v);
                        }
                }
        }
    }
}

// gemm3: R8-proven 128x128 BK=64 2-barrier kernel, tanh + f32 scatter out.
template<int K, int N>
__global__ __launch_bounds__(256) void gemm128_k(
    const unsigned short* __restrict__ A, const unsigned short* __restrict__ Bt,
    const float* __restrict__ bias, float* __restrict__ Outp,
    const int* __restrict__ ctrl, const int* __restrict__ t128E,
    const int* __restrict__ t128B, const int* __restrict__ perm)
{
    if ((int)blockIdx.x >= ctrl[14]) return;
    const int e = t128E[blockIdx.x];
    const int rowBase = t128B[blockIdx.x];
    const int n0 = blockIdx.y * 128;

    __shared__ unsigned short Als[128 * 64];
    __shared__ unsigned short Bls[128 * 64];

    const int tid = threadIdx.x;
    const int lane = tid & 63;
    const int w = tid >> 6;
    const int wm = w >> 1, wn = w & 1;
    const int lr = lane & 15, lh = lane >> 4;

    f32x4 acc[4][4] = {};

    const int tr = tid >> 3;
    const int tc = tid & 7;
    const int cs = (tc ^ (tr & 7)) * 8;
    const unsigned short* As = A + (size_t)(rowBase + tr) * K + cs;
    const unsigned short* Bs = Bt + ((size_t)e * N + n0 + tr) * K + cs;
    const int ldst = tr * 64 + tc * 8;

    for (int kq = 0; kq < K / 64; ++kq) {
        const int k0 = kq * 64;
        __syncthreads();
#pragma unroll
        for (int j = 0; j < 4; ++j) {
            gll16(As + (size_t)(j * 32) * K + k0, &Als[j * 2048 + ldst]);
            gll16(Bs + (size_t)(j * 32) * K + k0, &Bls[j * 2048 + ldst]);
        }
        __syncthreads();
#pragma unroll
        for (int kk = 0; kk < 2; ++kk) {
            const int ksl = ((kk * 4 + lh) ^ (lr & 7)) * 8;
            bf16x8 afr[4], bfr[4];
#pragma unroll
            for (int mi = 0; mi < 4; ++mi)
                afr[mi] = *(const bf16x8*)&Als[(wm * 64 + mi * 16 + lr) * 64 + ksl];
#pragma unroll
            for (int ni = 0; ni < 4; ++ni)
                bfr[ni] = *(const bf16x8*)&Bls[(wn * 64 + ni * 16 + lr) * 64 + ksl];
#pragma unroll
            for (int mi = 0; mi < 4; ++mi)
#pragma unroll
                for (int ni = 0; ni < 4; ++ni)
                    acc[mi][ni] = __builtin_amdgcn_mfma_f32_16x16x32_bf16(
                        afr[mi], bfr[ni], acc[mi][ni], 0, 0, 0);
        }
    }

    float bv[4];
    int colv[4];
#pragma unroll
    for (int ni = 0; ni < 4; ++ni) {
        colv[ni] = n0 + wn * 64 + ni * 16 + lr;
        bv[ni] = bias[e * N + colv[ni]];
    }
#pragma unroll
    for (int mi = 0; mi < 4; ++mi) {
#pragma unroll
        for (int r = 0; r < 4; ++r) {
            int rowL = wm * 64 + mi * 16 + lh * 4 + r;
            int orow = perm[rowBase + rowL];
#pragma unroll
            for (int ni = 0; ni < 4; ++ni) {
                float v = fast_tanh(acc[mi][ni][r] + bv[ni]);
                Outp[(size_t)orow * N + colv[ni]] = v;
            }
        }
    }
}

extern "C" void kernel_launch(void* const* d_in, const int* in_sizes, int n_in,
                              void* d_out, int out_size, void* d_ws, size_t ws_size,
                              hipStream_t stream) {
    const float* x  = (const float*)d_in[0];
    const int*   cmd= (const int*)d_in[1];
    const float* W1 = (const float*)d_in[2];
    const float* b1 = (const float*)d_in[3];
    const float* W2 = (const float*)d_in[4];
    const float* b2 = (const float*)d_in[5];
    const float* W3 = (const float*)d_in[6];
    const float* b3 = (const float*)d_in[7];
    float* out = (float*)d_out;

    char* w = (char*)d_ws;
    int* ctrl  = (int*)w;
    int* t256E = ctrl + 64;
    int* t256B = ctrl + 160;
    int* t128E = ctrl + 256;
    int* t128B = ctrl + 448;
    int* perm  = ctrl + 768;    // 16896 ints, ends < 131072 B
    unsigned short* Wt1 = (unsigned short*)(w + 131072);
    unsigned short* Wt2 = (unsigned short*)(w + 131072 + 4194304);
    unsigned short* Wt3 = (unsigned short*)(w + 131072 + 12582912);
    unsigned short* h1  = (unsigned short*)(w + 131072 + 16777216);
    unsigned short* h2  = h1 + (size_t)16896 * HID;
    unsigned short* xp  = h2;   // aliases h2 (xp dead before gemm2 writes h2)

    plan_all_k<<<1, 256, 0, stream>>>(cmd, ctrl, t256E, t256B, t128E, t128B);
    scatter_k<<<B_N / 256, 256, 0, stream>>>(cmd, ctrl, perm);
    prep_data_k<<<8192 + 4224, 256, 0, stream>>>(W1, W2, W3, Wt1, Wt2, Wt3,
                                                 x, xp, perm, ctrl);

    gemm8_k<DIN><<<dim3(MAXT256, 4), 512, 0, stream>>>(
        xp, Wt1, b1, h1, ctrl, t256E, t256B);
    gemm8_k<HID><<<dim3(MAXT256, 4), 512, 0, stream>>>(
        h1, Wt2, b2, h2, ctrl, t256E, t256B);
    gemm128_k<HID, DOUT><<<dim3(MAXT128, 4), 256, 0, stream>>>(
        h2, Wt3, b3, out, ctrl, t128E, t128B, perm);
}

// Round 15
// 163.772 us; speedup vs baseline: 1.1320x; 1.1320x over previous
//
#include <hip/hip_runtime.h>

// Branch MLP: B=16384 rows, E=4 experts, 512->1024->1024->512, relu/relu/tanh.
// Bucket rows by expert, pad segments to 128-row tiles w/ duplicate rows,
// 3 bf16-MFMA GEMM passes. Weights pre-transposed bf16 [E][N][K]; x
// pre-gathered to permuted bf16 xp. GEMM: R8-proven BM=BN=128, BK=64, 4 waves,
// single-buffer 2-barrier loop, chunk-XOR LDS swizzle (bank-conflict-free).
// NEW (R15): bijective chunked XCD swizzle on the gemm grids — XCD x gets
// tiles [17x,17x+17) x all N-panels, so each XCD's A-slab + B-panels fit its
// private 4MB L2 (R8's gemm1 fetched 69MB vs ~21MB compulsory).
//
// Workspace (86.1 MB):
//   ctrl[64] | tileExpert[160] | tileBase[160] | perm[16896]
//   Wt1 (4.19MB) | Wt2 (8.39MB) | Wt3 (4.19MB) | h1 (34.6MB) | h2 (34.6MB)
//   xp (17.3MB) aliases h2 (xp dead before gemm2 writes h2).

#define B_N   16384
#define DIN   512
#define HID   1024
#define DOUT  512
#define MAXTILES 136

typedef __attribute__((ext_vector_type(8))) short bf16x8;
typedef __attribute__((ext_vector_type(4))) float f32x4;
typedef __attribute__((address_space(3))) unsigned int lds_u32;
typedef const __attribute__((address_space(1))) unsigned int glb_u32;

__device__ __forceinline__ void gll16(const void* g, void* l) {
    __builtin_amdgcn_global_load_lds((glb_u32*)g, (lds_u32*)l, 16, 0, 0);
}

__device__ __forceinline__ unsigned short f2bf(float f) {
    unsigned int u = __float_as_uint(f);
    u += 0x7FFFu + ((u >> 16) & 1u);   // RNE
    return (unsigned short)(u >> 16);
}

__device__ __forceinline__ float fast_tanh(float x) {
    x = fminf(fmaxf(x, -9.0f), 9.0f);
    float t = __builtin_amdgcn_exp2f(x * 2.8853900817779268f);
    return (t - 1.0f) * __builtin_amdgcn_rcpf(t + 1.0f);
}

// One block: histogram cmd, zero cursors, build tile plan.
__global__ void plan_all_k(const int* __restrict__ cmd, int* __restrict__ ctrl,
                           int* __restrict__ tileExpert, int* __restrict__ tileBase) {
    __shared__ int h[4];
    int tid = threadIdx.x;
    if (tid < 4) h[tid] = 0;
    __syncthreads();
    int c0 = 0, c1 = 0, c2 = 0, c3 = 0;
    for (int i = tid; i < B_N; i += 256) {
        int e = cmd[i] & 3;
        c0 += (e == 0); c1 += (e == 1); c2 += (e == 2); c3 += (e == 3);
    }
    atomicAdd(&h[0], c0); atomicAdd(&h[1], c1);
    atomicAdd(&h[2], c2); atomicAdd(&h[3], c3);
    __syncthreads();
    if (tid == 0) {
        int P = 0, nt = 0;
        for (int e = 0; e < 4; ++e) {
            ctrl[e] = h[e];
            ctrl[4 + e] = 0;          // scatter cursors
            ctrl[8 + e] = P;
            int tiles = (h[e] + 127) >> 7;
            for (int t = 0; t < tiles; ++t) {
                tileExpert[nt] = e;
                tileBase[nt] = P + t * 128;
                ++nt;
            }
            P += tiles * 128;
        }
        ctrl[12] = P;                 // total padded rows
        ctrl[13] = nt;                // total tiles
    }
}

// Wave-aggregated scatter: one atomicAdd(popcount) per wave per expert.
__global__ void scatter_k(const int* __restrict__ cmd, int* __restrict__ ctrl,
                          int* __restrict__ perm) {
    int i = blockIdx.x * 256 + threadIdx.x;
    int e = cmd[i] & 3;
    int lane = threadIdx.x & 63;
#pragma unroll
    for (int ee = 0; ee < 4; ++ee) {
        unsigned long long mask = __ballot(e == ee);
        if (e == ee) {
            int leader = __ffsll((unsigned long long)mask) - 1;
            int rank = __popcll(mask & ((1ull << lane) - 1ull));
            int wbase = 0;
            if (lane == leader)
                wbase = atomicAdd(&ctrl[4 + ee], __popcll(mask));
            wbase = __builtin_amdgcn_readfirstlane(wbase);
            perm[ctrl[8 + ee] + wbase + rank] = i;
        }
    }
}

// Fused prep: blocks [0,8192) transpose+convert weights (packed uint writes);
// blocks [8192,12416) gather x -> permuted bf16 xp and fill pad perm entries.
__global__ __launch_bounds__(256) void prep_data_k(
    const float* __restrict__ W1, const float* __restrict__ W2,
    const float* __restrict__ W3, unsigned short* __restrict__ Wt1,
    unsigned short* __restrict__ Wt2, unsigned short* __restrict__ Wt3,
    const float* __restrict__ x, unsigned short* __restrict__ xp,
    int* __restrict__ perm, const int* __restrict__ ctrl)
{
    int b = blockIdx.x;
    if (b < 8192) {
        int e = b >> 11, r = b & 2047;
        const float* W; unsigned short* Wt; int KD, ND, kt, nt;
        if (r < 512)       { W = W1; Wt = Wt1; KD = 512;  ND = 1024; kt = r & 15;           nt = r >> 4; }
        else if (r < 1536) { W = W2; Wt = Wt2; KD = 1024; ND = 1024; kt = (r - 512) & 31;   nt = (r - 512) >> 5; }
        else               { W = W3; Wt = Wt3; KD = 1024; ND = 512;  kt = (r - 1536) & 31;  nt = (r - 1536) >> 5; }
        __shared__ float t[32][33];
        size_t base = (size_t)e * KD * ND;
        int k0 = kt * 32, n0 = nt * 32;
        int tx = threadIdx.x & 31, ty = threadIdx.x >> 5;
#pragma unroll
        for (int s = 0; s < 4; ++s)
            t[ty + s * 8][tx] = W[base + (size_t)(k0 + ty + s * 8) * ND + n0 + tx];
        __syncthreads();
        // packed write: thread -> k-pair tx2, n-row ny (+16 per s); uint = 2 bf16
        int tx2 = (threadIdx.x & 15) * 2, ny = threadIdx.x >> 4;
#pragma unroll
        for (int s = 0; s < 2; ++s) {
            int n = ny + s * 16;
            unsigned int v = (unsigned)f2bf(t[tx2][n])
                           | ((unsigned)f2bf(t[tx2 + 1][n]) << 16);
            *(unsigned int*)&Wt[base + (size_t)(n0 + n) * KD + k0 + tx2] = v;
        }
    } else {
        int g = b - 8192;
        int p = g * 4 + (int)(threadIdx.x >> 6);
        if (p >= ctrl[12]) return;
        int lane = threadIdx.x & 63;
        int e = (p >= ctrl[9]) + (p >= ctrl[10]) + (p >= ctrl[11]);
        int segBase = ctrl[8 + e];
        int src;
        if (p < segBase + ctrl[e]) {
            src = perm[p];
        } else {
            src = perm[segBase];              // duplicate a valid same-expert row
            if (lane == 0) perm[p] = src;     // so gemm3 scatter-epilogue is safe
        }
        const float* xr = x + (size_t)src * DIN + lane * 8;
        float4 a = *(const float4*)xr;
        float4 c = *(const float4*)(xr + 4);
        uint4 o;
        o.x = (unsigned)f2bf(a.x) | ((unsigned)f2bf(a.y) << 16);
        o.y = (unsigned)f2bf(a.z) | ((unsigned)f2bf(a.w) << 16);
        o.z = (unsigned)f2bf(c.x) | ((unsigned)f2bf(c.y) << 16);
        o.w = (unsigned)f2bf(c.z) | ((unsigned)f2bf(c.w) << 16);
        *(uint4*)(xp + (size_t)p * DIN + lane * 8) = o;
    }
}

// Grouped GEMM: C = act(A @ Wt[e]^T + b[e]). BM=BN=128, BK=64, 256 thr =
// 4 waves (2x2 quadrants of 64x64, 4x4 frags, 2 k-halves of 16x16x32).
// Single-buffer, 2 barriers per K-step. Chunk-XOR involution: LDS slot s of
// row r holds global 16B-chunk (s ^ (r&7)); ds_read XORs the same. gll16 LDS
// dest stays tid*16B-linear per call.
// R15: chunked XCD swizzle — linear block id l, swz=(l&7)*(17*PN)+(l>>3);
// tile=swz/PN, panel=swz%PN. XCD x covers tiles [17x,17x+17) x all panels,
// so its A-slab and B-panels stay resident in the per-XCD 4MB L2.
template<int K, int N, int PN, int ACT, bool SCATTER_OUT>
__global__ __launch_bounds__(256) void gemm_k(
    const unsigned short* __restrict__ A, const unsigned short* __restrict__ Bt,
    const float* __restrict__ bias, void* __restrict__ Outp,
    const int* __restrict__ ctrl, const int* __restrict__ tileExpert,
    const int* __restrict__ tileBase, const int* __restrict__ perm)
{
    static_assert(PN == 4 || PN == 8, "PN power of 2");
    const int l = (int)blockIdx.x + MAXTILES * (int)blockIdx.y;
    const int swz = (l & 7) * (17 * PN) + (l >> 3);
    const int tile = swz / PN;              // PN pow2 -> shift
    const int panel = swz & (PN - 1);
    if (tile >= ctrl[13]) return;
    const int e = tileExpert[tile];
    const int rowBase = tileBase[tile];
    const int n0 = panel * 128;

    __shared__ unsigned short Als[128 * 64];   // 16 KB, rows of 128B
    __shared__ unsigned short Bls[128 * 64];

    const int tid = threadIdx.x;
    const int lane = tid & 63;
    const int w = tid >> 6;
    const int wm = w >> 1, wn = w & 1;
    const int lr = lane & 15, lh = lane >> 4;

    f32x4 acc[4][4] = {};

    // Staging: thread t -> row tr (within 32-row call-block), chunk-slot tc.
    // 4 calls/operand cover rows +0,+32,+64,+96 (LDS byte = j*4096 + tid*16,
    // linear per call). Source chunk = tc ^ (tr&7)  (row&7 == tr&7).
    const int tr = tid >> 3;                  // 0..31
    const int tc = tid & 7;                   // chunk slot 0..7
    const int cs = (tc ^ (tr & 7)) * 8;       // source ushort offset in row
    const unsigned short* As = A + (size_t)(rowBase + tr) * K + cs;
    const unsigned short* Bs = Bt + ((size_t)e * N + n0 + tr) * K + cs;
    const int ldst = tr * 64 + tc * 8;        // ushort idx; byte == tid*16

    constexpr int NK = K / 64;
    for (int kq = 0; kq < NK; ++kq) {
        const int k0 = kq * 64;
        __syncthreads();                      // prior reads of buffer done
#pragma unroll
        for (int j = 0; j < 4; ++j) {
            gll16(As + (size_t)(j * 32) * K + k0, &Als[j * 2048 + ldst]);
            gll16(Bs + (size_t)(j * 32) * K + k0, &Bls[j * 2048 + ldst]);
        }
        __syncthreads();                      // drains vmcnt before release
#pragma unroll
        for (int kk = 0; kk < 2; ++kk) {
            const int ksl = ((kk * 4 + lh) ^ (lr & 7)) * 8;   // swizzled read
            bf16x8 afr[4], bfr[4];
#pragma unroll
            for (int mi = 0; mi < 4; ++mi)
                afr[mi] = *(const bf16x8*)&Als[(wm * 64 + mi * 16 + lr) * 64 + ksl];
#pragma unroll
            for (int ni = 0; ni < 4; ++ni)
                bfr[ni] = *(const bf16x8*)&Bls[(wn * 64 + ni * 16 + lr) * 64 + ksl];
#pragma unroll
            for (int mi = 0; mi < 4; ++mi)
#pragma unroll
                for (int ni = 0; ni < 4; ++ni)
                    acc[mi][ni] = __builtin_amdgcn_mfma_f32_16x16x32_bf16(
                        afr[mi], bfr[ni], acc[mi][ni], 0, 0, 0);
        }
    }

    float bv[4];
    int colv[4];
#pragma unroll
    for (int ni = 0; ni < 4; ++ni) {
        colv[ni] = n0 + wn * 64 + ni * 16 + lr;
        bv[ni] = bias[e * N + colv[ni]];
    }
#pragma unroll
    for (int mi = 0; mi < 4; ++mi) {
#pragma unroll
        for (int r = 0; r < 4; ++r) {
            int rowL = wm * 64 + mi * 16 + lh * 4 + r;   // C/D: row=(lane>>4)*4+reg
            int gRow = rowBase + rowL;
            int orow = SCATTER_OUT ? perm[gRow] : gRow;
#pragma unroll
            for (int ni = 0; ni < 4; ++ni) {
                float v = acc[mi][ni][r] + bv[ni];
                if (ACT == 0) v = fmaxf(v, 0.0f);
                else          v = fast_tanh(v);
                if (SCATTER_OUT)
                    ((float*)Outp)[(size_t)orow * N + colv[ni]] = v;
                else
                    ((unsigned short*)Outp)[(size_t)orow * N + colv[ni]] = f2bf(v);
            }
        }
    }
}

extern "C" void kernel_launch(void* const* d_in, const int* in_sizes, int n_in,
                              void* d_out, int out_size, void* d_ws, size_t ws_size,
                              hipStream_t stream) {
    const float* x  = (const float*)d_in[0];
    const int*   cmd= (const int*)d_in[1];
    const float* W1 = (const float*)d_in[2];
    const float* b1 = (const float*)d_in[3];
    const float* W2 = (const float*)d_in[4];
    const float* b2 = (const float*)d_in[5];
    const float* W3 = (const float*)d_in[6];
    const float* b3 = (const float*)d_in[7];
    float* out = (float*)d_out;

    char* w = (char*)d_ws;
    int* ctrl       = (int*)w;
    int* tileExpert = ctrl + 64;
    int* tileBase   = ctrl + 224;
    int* perm       = ctrl + 512;                         // 16896 ints
    unsigned short* Wt1 = (unsigned short*)(w + 131072);
    unsigned short* Wt2 = (unsigned short*)(w + 131072 + 4194304);
    unsigned short* Wt3 = (unsigned short*)(w + 131072 + 12582912);
    unsigned short* h1  = (unsigned short*)(w + 131072 + 16777216);
    unsigned short* h2  = h1 + (size_t)16896 * HID;       // 34.6 MB each
    unsigned short* xp  = h2;                             // aliases h2 (WAR-safe)

    plan_all_k<<<1, 256, 0, stream>>>(cmd, ctrl, tileExpert, tileBase);
    scatter_k<<<B_N / 256, 256, 0, stream>>>(cmd, ctrl, perm);
    prep_data_k<<<8192 + 4224, 256, 0, stream>>>(W1, W2, W3, Wt1, Wt2, Wt3,
                                                 x, xp, perm, ctrl);

    gemm_k<DIN, HID, 8, 0, false><<<dim3(MAXTILES, 8), 256, 0, stream>>>(
        xp, Wt1, b1, h1, ctrl, tileExpert, tileBase, perm);
    gemm_k<HID, HID, 8, 0, false><<<dim3(MAXTILES, 8), 256, 0, stream>>>(
        h1, Wt2, b2, h2, ctrl, tileExpert, tileBase, perm);
    gemm_k<HID, DOUT, 4, 1, true><<<dim3(MAXTILES, 4), 256, 0, stream>>>(
        h2, Wt3, b3, out, ctrl, tileExpert, tileBase, perm);
}